// Round 1
// baseline (270.684 us; speedup 1.0000x reference)
//
#include <hip/hip_runtime.h>
#include <cfloat>

#define M_UP   32768
#define N_DOWN 8192
#define UPC    128
#define DOWNC  256
#define OUTC   128
#define NCHUNK 8
#define CHUNK  (N_DOWN / NCHUNK)   // 1024
#define G      8                   // selection group size

__device__ __forceinline__ void fma4(float4& acc, float s, const float4 w) {
    acc.x = fmaf(s, w.x, acc.x);
    acc.y = fmaf(s, w.y, acc.y);
    acc.z = fmaf(s, w.z, acc.z);
    acc.w = fmaf(s, w.w, acc.w);
}

// Branchless stable top-3 insert with index tracking.
// Strict < everywhere => earlier-inserted wins ties (stable in scan order),
// matching jax.lax.top_k's lower-index-first tie-break.
__device__ __forceinline__ void top3_bl(float s, int idx,
                                        float& d0, float& d1, float& d2,
                                        int& i0, int& i1, int& i2) {
    bool c0 = s < d0, c1 = s < d1, c2 = s < d2;
    float n0 = fminf(d0, s);
    float n1 = __builtin_amdgcn_fmed3f(d0, d1, s);
    float n2 = __builtin_amdgcn_fmed3f(d1, d2, s);
    int m0 = c0 ? idx : i0;
    int m1 = c0 ? i0 : (c1 ? idx : i1);
    int m2 = c1 ? i1 : (c2 ? idx : i2);
    d0 = n0; d1 = n1; d2 = n2;
    i0 = m0; i1 = m1; i2 = m2;
}

// ---------------------------------------------------------------------------
// K0: prep — transpose weights for coalesced float4 GEMM reads, and pack
// down_points into float4 (16B-aligned) so the knn scan can use wave-uniform
// scalar loads (s_load_dwordx16 batches) instead of LDS staging.
// ---------------------------------------------------------------------------
__global__ __launch_bounds__(256) void prep(
        const float* __restrict__ W_up, const float* __restrict__ W_down,
        const float* __restrict__ down_points,
        float* __restrict__ wt_up, float* __restrict__ wt_down,
        float4* __restrict__ pts4) {
    int e = blockIdx.x * 256 + threadIdx.x;
    if (e < DOWNC * OUTC) {
        int k = e >> 7, c = e & 127;
        wt_down[e] = W_down[c * DOWNC + k];
    } else if (e < DOWNC * OUTC + UPC * OUTC) {
        int e2 = e - DOWNC * OUTC;
        int k = e2 >> 7, c = e2 & 127;
        wt_up[e2] = W_up[c * UPC + k];
    } else {
        int p = e - (DOWNC * OUTC + UPC * OUTC);
        if (p < N_DOWN) {
            pts4[p] = make_float4(down_points[3 * p], down_points[3 * p + 1],
                                  down_points[3 * p + 2], 0.f);
        }
    }
}

// ---------------------------------------------------------------------------
// K1: down_f = down_features @ W_down.T + b_down  (8192 x 128)
// ---------------------------------------------------------------------------
__global__ __launch_bounds__(256) void down_proj(
        const float* __restrict__ A, const float* __restrict__ WT,
        const float* __restrict__ bias, float* __restrict__ down_f) {
    const int c4 = threadIdx.x & 31;
    const int rr = threadIdx.x >> 5;
    const int r0 = blockIdx.x * 16 + rr;
    const int r1 = r0 + 8;
    const float* A0 = A + r0 * DOWNC;
    const float* A1 = A + r1 * DOWNC;
    float4 acc0 = {0.f, 0.f, 0.f, 0.f};
    float4 acc1 = {0.f, 0.f, 0.f, 0.f};
    for (int k = 0; k < DOWNC; k += 4) {
        float4 a0 = *(const float4*)(A0 + k);
        float4 a1 = *(const float4*)(A1 + k);
        const float4* wp = (const float4*)(WT + k * OUTC) + c4;
        float4 w0 = wp[0], w1 = wp[32], w2 = wp[64], w3 = wp[96];
        fma4(acc0, a0.x, w0); fma4(acc0, a0.y, w1);
        fma4(acc0, a0.z, w2); fma4(acc0, a0.w, w3);
        fma4(acc1, a1.x, w0); fma4(acc1, a1.y, w1);
        fma4(acc1, a1.z, w2); fma4(acc1, a1.w, w3);
    }
    float4 b = ((const float4*)bias)[c4];
    acc0.x += b.x; acc0.y += b.y; acc0.z += b.z; acc0.w += b.w;
    acc1.x += b.x; acc1.y += b.y; acc1.z += b.z; acc1.w += b.w;
    ((float4*)down_f)[r0 * 32 + c4] = acc0;
    ((float4*)down_f)[r1 * 32 + c4] = acc1;
}

// ---------------------------------------------------------------------------
// K2: partial 3-NN, branchless grouped selection — LDS-free.
// Per thread: 1 query, scan CHUNK points in groups of G via wave-uniform
// reads of the packed float4 point array. The group index g is a uniform
// induction variable, so the compiler emits scalar loads (s_load) through
// the K$, bypassing the per-CU LDS pipe that bounded the previous version
// (broadcast ds_read_b128 still costs ~8 cy/inst of LDS writeback).
// Track top-3 groups by group-min, then exactly refine the <=3 winning
// groups (per-lane vector loads from the L1-resident 16KB chunk).
// ---------------------------------------------------------------------------
__global__ __launch_bounds__(256) void knn_partial(
        const float* __restrict__ up_points,
        const float4* __restrict__ pts4,
        float* __restrict__ part_d,             // [NCHUNK][M_UP][3]
        int* __restrict__ part_i) {
    const int base = blockIdx.y * CHUNK;
    const float4* __restrict__ cp = pts4 + base;
    const int m = blockIdx.x * 256 + threadIdx.x;
    const float qx = up_points[3 * m];
    const float qy = up_points[3 * m + 1];
    const float qz = up_points[3 * m + 2];

    float gd0 = FLT_MAX, gd1 = FLT_MAX, gd2 = FLT_MAX;
    int gi0 = 0, gi1 = 0, gi2 = 0;
    for (int g = 0; g < CHUNK; g += G) {
        float s[G];
        #pragma unroll
        for (int j = 0; j < G; ++j) {
            float4 p = cp[g + j];            // uniform address -> s_load
            float dx = qx - p.x, dy = qy - p.y, dz = qz - p.z;
            s[j] = fmaf(dz, dz, fmaf(dy, dy, dx * dx));
        }
        float m01 = fminf(s[0], s[1]), m23 = fminf(s[2], s[3]);
        float m45 = fminf(s[4], s[5]), m67 = fminf(s[6], s[7]);
        float gmin = fminf(fminf(m01, m23), fminf(m45, m67));
        top3_bl(gmin, g, gd0, gd1, gd2, gi0, gi1, gi2);
    }

    // exact refine over the 3 winning groups (24 points, divergent loads)
    float D0 = FLT_MAX, D1 = FLT_MAX, D2 = FLT_MAX;
    int I0 = 0, I1 = 0, I2 = 0;
    int bases[3] = {gi0, gi1, gi2};
    #pragma unroll
    for (int t = 0; t < 3; ++t) {
        const int b = bases[t];
        #pragma unroll
        for (int j = 0; j < G; ++j) {
            float4 p = cp[b + j];
            float dx = qx - p.x, dy = qy - p.y, dz = qz - p.z;
            float s = fmaf(dz, dz, fmaf(dy, dy, dx * dx));
            top3_bl(s, base + b + j, D0, D1, D2, I0, I1, I2);
        }
    }
    const int o = (blockIdx.y * M_UP + m) * 3;
    part_d[o] = D0; part_d[o + 1] = D1; part_d[o + 2] = D2;
    part_i[o] = I0; part_i[o + 1] = I1; part_i[o + 2] = I2;
}

// ---------------------------------------------------------------------------
// K3: fused up-projection + top-3 merge + interpolation + bias + add.
// ---------------------------------------------------------------------------
__global__ __launch_bounds__(256) void up_fused(
        const float* __restrict__ A, const float* __restrict__ WT,
        const float* __restrict__ bias, const float* __restrict__ down_f,
        const float* __restrict__ part_d, const int* __restrict__ part_i,
        float* __restrict__ out) {
    const int c4 = threadIdx.x & 31;
    const int rr = threadIdx.x >> 5;
    const int q0 = blockIdx.x * 16 + rr;
    const int q1 = q0 + 8;
    const float* A0 = A + q0 * UPC;
    const float* A1 = A + q1 * UPC;
    float4 acc0 = {0.f, 0.f, 0.f, 0.f};
    float4 acc1 = {0.f, 0.f, 0.f, 0.f};
    for (int k = 0; k < UPC; k += 4) {
        float4 a0 = *(const float4*)(A0 + k);
        float4 a1 = *(const float4*)(A1 + k);
        const float4* wp = (const float4*)(WT + k * OUTC) + c4;
        float4 w0 = wp[0], w1 = wp[32], w2 = wp[64], w3 = wp[96];
        fma4(acc0, a0.x, w0); fma4(acc0, a0.y, w1);
        fma4(acc0, a0.z, w2); fma4(acc0, a0.w, w3);
        fma4(acc1, a1.x, w0); fma4(acc1, a1.y, w1);
        fma4(acc1, a1.z, w2); fma4(acc1, a1.w, w3);
    }
    const float4 b = ((const float4*)bias)[c4];
    const float4* df4 = (const float4*)down_f;
    #pragma unroll
    for (int t = 0; t < 2; ++t) {
        const int q = t ? q1 : q0;
        float4 acc = t ? acc1 : acc0;
        float D0 = FLT_MAX, D1 = FLT_MAX, D2 = FLT_MAX;
        int I0 = 0, I1 = 0, I2 = 0;
        #pragma unroll
        for (int s = 0; s < NCHUNK; ++s) {
            const int o = (s * M_UP + q) * 3;
            #pragma unroll
            for (int j = 0; j < 3; ++j) {
                float d = part_d[o + j];
                int gi = part_i[o + j];
                top3_bl(d, gi, D0, D1, D2, I0, I1, I2);
            }
        }
        float r0 = 1.f / (D0 + 1e-8f);
        float r1 = 1.f / (D1 + 1e-8f);
        float r2 = 1.f / (D2 + 1e-8f);
        float rs = (r0 + r1) + r2;
        float w0 = r0 / rs, w1 = r1 / rs, w2 = r2 / rs;
        float4 f0 = df4[I0 * 32 + c4];
        float4 f1 = df4[I1 * 32 + c4];
        float4 f2 = df4[I2 * 32 + c4];
        float4 res;
        res.x = acc.x + b.x + fmaf(w0, f0.x, fmaf(w1, f1.x, w2 * f2.x));
        res.y = acc.y + b.y + fmaf(w0, f0.y, fmaf(w1, f1.y, w2 * f2.y));
        res.z = acc.z + b.z + fmaf(w0, f0.z, fmaf(w1, f1.z, w2 * f2.z));
        res.w = acc.w + b.w + fmaf(w0, f0.w, fmaf(w1, f1.w, w2 * f2.w));
        ((float4*)out)[q * 32 + c4] = res;
    }
}

extern "C" void kernel_launch(void* const* d_in, const int* in_sizes, int n_in,
                              void* d_out, int out_size, void* d_ws, size_t ws_size,
                              hipStream_t stream) {
    const float* up_points     = (const float*)d_in[0];
    const float* up_features   = (const float*)d_in[1];
    const float* down_points   = (const float*)d_in[2];
    const float* down_features = (const float*)d_in[3];
    const float* W_up          = (const float*)d_in[4];
    const float* b_up          = (const float*)d_in[5];
    const float* W_down        = (const float*)d_in[6];
    const float* b_down        = (const float*)d_in[7];
    float* out = (float*)d_out;

    float4* pts4   = (float4*)d_ws;                        // 8192*16B = 128KB (64B-aligned)
    float* wt_down = (float*)(pts4 + N_DOWN);              // 256*128
    float* wt_up   = wt_down + DOWNC * OUTC;               // 128*128
    float* down_f  = wt_up + UPC * OUTC;                   // 8192*128
    float* part_d  = down_f + N_DOWN * OUTC;               // NCHUNK*32768*3
    int*   part_i  = (int*)(part_d + NCHUNK * M_UP * 3);   // NCHUNK*32768*3
    // total ~10.9 MB

    prep<<<(DOWNC * OUTC + UPC * OUTC + N_DOWN) / 256, 256, 0, stream>>>(
        W_up, W_down, down_points, wt_up, wt_down, pts4);
    down_proj<<<N_DOWN / 16, 256, 0, stream>>>(
        down_features, wt_down, b_down, down_f);
    knn_partial<<<dim3(M_UP / 256, NCHUNK), 256, 0, stream>>>(
        up_points, pts4, part_d, part_i);
    up_fused<<<M_UP / 16, 256, 0, stream>>>(
        up_features, wt_up, b_up, down_f, part_d, part_i, out);
}

// Round 3
// 242.578 us; speedup vs baseline: 1.1159x; 1.1159x over previous
//
#include <hip/hip_runtime.h>
#include <cfloat>

#define M_UP   32768
#define N_DOWN 8192
#define UPC    128
#define DOWNC  256
#define OUTC   128
#define NCHUNK 8
#define CHUNK  (N_DOWN / NCHUNK)   // 1024
#define G      8                   // selection group size
#define Q      2                   // queries per thread (amortizes LDS reads)

__device__ __forceinline__ void fma4(float4& acc, float s, const float4 w) {
    acc.x = fmaf(s, w.x, acc.x);
    acc.y = fmaf(s, w.y, acc.y);
    acc.z = fmaf(s, w.z, acc.z);
    acc.w = fmaf(s, w.w, acc.w);
}

// Branchless stable top-3 insert with index tracking.
// Strict < everywhere => earlier-inserted wins ties (stable in scan order),
// matching jax.lax.top_k's lower-index-first tie-break.
__device__ __forceinline__ void top3_bl(float s, int idx,
                                        float& d0, float& d1, float& d2,
                                        int& i0, int& i1, int& i2) {
    bool c0 = s < d0, c1 = s < d1, c2 = s < d2;
    float n0 = fminf(d0, s);
    float n1 = __builtin_amdgcn_fmed3f(d0, d1, s);
    float n2 = __builtin_amdgcn_fmed3f(d1, d2, s);
    int m0 = c0 ? idx : i0;
    int m1 = c0 ? i0 : (c1 ? idx : i1);
    int m2 = c1 ? i1 : (c2 ? idx : i2);
    d0 = n0; d1 = n1; d2 = n2;
    i0 = m0; i1 = m1; i2 = m2;
}

// ---------------------------------------------------------------------------
// K0: transpose weights for coalesced float4 GEMM reads.
// ---------------------------------------------------------------------------
__global__ __launch_bounds__(256) void transpose_w(
        const float* __restrict__ W_up, const float* __restrict__ W_down,
        float* __restrict__ wt_up, float* __restrict__ wt_down) {
    int e = blockIdx.x * 256 + threadIdx.x;
    if (e < DOWNC * OUTC) {
        int k = e >> 7, c = e & 127;
        wt_down[e] = W_down[c * DOWNC + k];
    } else {
        int e2 = e - DOWNC * OUTC;
        int k = e2 >> 7, c = e2 & 127;
        wt_up[e2] = W_up[c * UPC + k];
    }
}

// ---------------------------------------------------------------------------
// K1: down_f = down_features @ W_down.T + b_down  (8192 x 128)
// ---------------------------------------------------------------------------
__global__ __launch_bounds__(256) void down_proj(
        const float* __restrict__ A, const float* __restrict__ WT,
        const float* __restrict__ bias, float* __restrict__ down_f) {
    const int c4 = threadIdx.x & 31;
    const int rr = threadIdx.x >> 5;
    const int r0 = blockIdx.x * 16 + rr;
    const int r1 = r0 + 8;
    const float* A0 = A + r0 * DOWNC;
    const float* A1 = A + r1 * DOWNC;
    float4 acc0 = {0.f, 0.f, 0.f, 0.f};
    float4 acc1 = {0.f, 0.f, 0.f, 0.f};
    for (int k = 0; k < DOWNC; k += 4) {
        float4 a0 = *(const float4*)(A0 + k);
        float4 a1 = *(const float4*)(A1 + k);
        const float4* wp = (const float4*)(WT + k * OUTC) + c4;
        float4 w0 = wp[0], w1 = wp[32], w2 = wp[64], w3 = wp[96];
        fma4(acc0, a0.x, w0); fma4(acc0, a0.y, w1);
        fma4(acc0, a0.z, w2); fma4(acc0, a0.w, w3);
        fma4(acc1, a1.x, w0); fma4(acc1, a1.y, w1);
        fma4(acc1, a1.z, w2); fma4(acc1, a1.w, w3);
    }
    float4 b = ((const float4*)bias)[c4];
    acc0.x += b.x; acc0.y += b.y; acc0.z += b.z; acc0.w += b.w;
    acc1.x += b.x; acc1.y += b.y; acc1.z += b.z; acc1.w += b.w;
    ((float4*)down_f)[r0 * 32 + c4] = acc0;
    ((float4*)down_f)[r1 * 32 + c4] = acc1;
}

// ---------------------------------------------------------------------------
// K2: partial 3-NN. Broadcast point-read pipe is the bottleneck (R0: LDS
// ~12cy/b128 -> 82us; R1: L1 broadcast path ~14cy -> 98us). Fix = fewer
// wave-level reads:
//   - Q=2 queries per thread: point reads amortized across 2 queries (x0.5)
//   - SoA chunk in LDS: 6 b128 per 8 points instead of 8 (x0.75)
// Scan reads: 4.19M -> 1.57M wave-level b128 (~31us of LDS pipe) vs a ~28us
// VALU floor. NCHUNK stays 8 so workspace size matches the proven R0 layout.
// Group-min top-3 selection + exact refine of <=3 winning groups per query:
// any group with min < true-d2 must contain a top-2 point, so <=3 groups can
// precede the group holding the true 3rd neighbor => winners contain the
// exact top-3. Partials stored as (d, idx-as-float) float2 pairs.
// ---------------------------------------------------------------------------
__global__ __launch_bounds__(256) void knn_partial(
        const float* __restrict__ up_points,
        const float* __restrict__ down_points,
        float2* __restrict__ part) {            // [NCHUNK][M_UP][3]
    __shared__ __align__(16) float sx[CHUNK];
    __shared__ __align__(16) float sy[CHUNK];
    __shared__ __align__(16) float sz[CHUNK];
    const int base = blockIdx.y * CHUNK;
    for (int t = threadIdx.x; t < CHUNK; t += 256) {
        int g = base + t;
        sx[t] = down_points[3 * g];
        sy[t] = down_points[3 * g + 1];
        sz[t] = down_points[3 * g + 2];
    }
    __syncthreads();

    const int m0 = blockIdx.x * (256 * Q) + threadIdx.x;
    const int m1 = m0 + 256;
    const float q0x = up_points[3 * m0];
    const float q0y = up_points[3 * m0 + 1];
    const float q0z = up_points[3 * m0 + 2];
    const float q1x = up_points[3 * m1];
    const float q1y = up_points[3 * m1 + 1];
    const float q1z = up_points[3 * m1 + 2];

    float a_gd0 = FLT_MAX, a_gd1 = FLT_MAX, a_gd2 = FLT_MAX;
    int   a_gi0 = 0, a_gi1 = 0, a_gi2 = 0;
    float b_gd0 = FLT_MAX, b_gd1 = FLT_MAX, b_gd2 = FLT_MAX;
    int   b_gi0 = 0, b_gi1 = 0, b_gi2 = 0;

    for (int g = 0; g < CHUNK; g += G) {
        float4 x0 = *(const float4*)&sx[g], x1 = *(const float4*)&sx[g + 4];
        float4 y0 = *(const float4*)&sy[g], y1 = *(const float4*)&sy[g + 4];
        float4 z0 = *(const float4*)&sz[g], z1 = *(const float4*)&sz[g + 4];
        float px[G] = {x0.x, x0.y, x0.z, x0.w, x1.x, x1.y, x1.z, x1.w};
        float py[G] = {y0.x, y0.y, y0.z, y0.w, y1.x, y1.y, y1.z, y1.w};
        float pz[G] = {z0.x, z0.y, z0.z, z0.w, z1.x, z1.y, z1.z, z1.w};
        float s0[G], s1[G];
        #pragma unroll
        for (int j = 0; j < G; ++j) {
            float dx0 = q0x - px[j], dy0 = q0y - py[j], dz0 = q0z - pz[j];
            s0[j] = fmaf(dz0, dz0, fmaf(dy0, dy0, dx0 * dx0));
            float dx1 = q1x - px[j], dy1 = q1y - py[j], dz1 = q1z - pz[j];
            s1[j] = fmaf(dz1, dz1, fmaf(dy1, dy1, dx1 * dx1));
        }
        float gm0 = fminf(fminf(fminf(s0[0], s0[1]), fminf(s0[2], s0[3])),
                          fminf(fminf(s0[4], s0[5]), fminf(s0[6], s0[7])));
        float gm1 = fminf(fminf(fminf(s1[0], s1[1]), fminf(s1[2], s1[3])),
                          fminf(fminf(s1[4], s1[5]), fminf(s1[6], s1[7])));
        top3_bl(gm0, g, a_gd0, a_gd1, a_gd2, a_gi0, a_gi1, a_gi2);
        top3_bl(gm1, g, b_gd0, b_gd1, b_gd2, b_gi0, b_gi1, b_gi2);
    }

    // exact refine over the 3 winning groups (24 points per query)
    #pragma unroll
    for (int qq = 0; qq < Q; ++qq) {
        const float qx = qq ? q1x : q0x;
        const float qy = qq ? q1y : q0y;
        const float qz = qq ? q1z : q0z;
        int bases[3];
        if (qq == 0) { bases[0] = a_gi0; bases[1] = a_gi1; bases[2] = a_gi2; }
        else         { bases[0] = b_gi0; bases[1] = b_gi1; bases[2] = b_gi2; }
        float D0 = FLT_MAX, D1 = FLT_MAX, D2 = FLT_MAX;
        int I0 = 0, I1 = 0, I2 = 0;
        #pragma unroll
        for (int t = 0; t < 3; ++t) {
            const int b = bases[t];
            float4 x0 = *(const float4*)&sx[b], x1 = *(const float4*)&sx[b + 4];
            float4 y0 = *(const float4*)&sy[b], y1 = *(const float4*)&sy[b + 4];
            float4 z0 = *(const float4*)&sz[b], z1 = *(const float4*)&sz[b + 4];
            float px[G] = {x0.x, x0.y, x0.z, x0.w, x1.x, x1.y, x1.z, x1.w};
            float py[G] = {y0.x, y0.y, y0.z, y0.w, y1.x, y1.y, y1.z, y1.w};
            float pz[G] = {z0.x, z0.y, z0.z, z0.w, z1.x, z1.y, z1.z, z1.w};
            #pragma unroll
            for (int j = 0; j < G; ++j) {
                float dx = qx - px[j], dy = qy - py[j], dz = qz - pz[j];
                float s = fmaf(dz, dz, fmaf(dy, dy, dx * dx));
                top3_bl(s, base + b + j, D0, D1, D2, I0, I1, I2);
            }
        }
        const int m = qq ? m1 : m0;
        const int o = (blockIdx.y * M_UP + m) * 3;
        part[o]     = make_float2(D0, __int_as_float(I0));
        part[o + 1] = make_float2(D1, __int_as_float(I1));
        part[o + 2] = make_float2(D2, __int_as_float(I2));
    }
}

// ---------------------------------------------------------------------------
// K3: fused up-projection + top-3 merge + interpolation + bias + add.
// ---------------------------------------------------------------------------
__global__ __launch_bounds__(256) void up_fused(
        const float* __restrict__ A, const float* __restrict__ WT,
        const float* __restrict__ bias, const float* __restrict__ down_f,
        const float2* __restrict__ part,
        float* __restrict__ out) {
    const int c4 = threadIdx.x & 31;
    const int rr = threadIdx.x >> 5;
    const int q0 = blockIdx.x * 16 + rr;
    const int q1 = q0 + 8;
    const float* A0 = A + q0 * UPC;
    const float* A1 = A + q1 * UPC;
    float4 acc0 = {0.f, 0.f, 0.f, 0.f};
    float4 acc1 = {0.f, 0.f, 0.f, 0.f};
    for (int k = 0; k < UPC; k += 4) {
        float4 a0 = *(const float4*)(A0 + k);
        float4 a1 = *(const float4*)(A1 + k);
        const float4* wp = (const float4*)(WT + k * OUTC) + c4;
        float4 w0 = wp[0], w1 = wp[32], w2 = wp[64], w3 = wp[96];
        fma4(acc0, a0.x, w0); fma4(acc0, a0.y, w1);
        fma4(acc0, a0.z, w2); fma4(acc0, a0.w, w3);
        fma4(acc1, a1.x, w0); fma4(acc1, a1.y, w1);
        fma4(acc1, a1.z, w2); fma4(acc1, a1.w, w3);
    }
    const float4 b = ((const float4*)bias)[c4];
    const float4* df4 = (const float4*)down_f;
    #pragma unroll
    for (int t = 0; t < 2; ++t) {
        const int q = t ? q1 : q0;
        float4 acc = t ? acc1 : acc0;
        float D0 = FLT_MAX, D1 = FLT_MAX, D2 = FLT_MAX;
        int I0 = 0, I1 = 0, I2 = 0;
        #pragma unroll
        for (int s = 0; s < NCHUNK; ++s) {
            const float2* p = part + (s * M_UP + q) * 3;
            #pragma unroll
            for (int j = 0; j < 3; ++j) {
                float2 v = p[j];
                top3_bl(v.x, __float_as_int(v.y), D0, D1, D2, I0, I1, I2);
            }
        }
        float r0 = 1.f / (D0 + 1e-8f);
        float r1 = 1.f / (D1 + 1e-8f);
        float r2 = 1.f / (D2 + 1e-8f);
        float rs = (r0 + r1) + r2;
        float w0 = r0 / rs, w1 = r1 / rs, w2 = r2 / rs;
        float4 f0 = df4[I0 * 32 + c4];
        float4 f1 = df4[I1 * 32 + c4];
        float4 f2 = df4[I2 * 32 + c4];
        float4 res;
        res.x = acc.x + b.x + fmaf(w0, f0.x, fmaf(w1, f1.x, w2 * f2.x));
        res.y = acc.y + b.y + fmaf(w0, f0.y, fmaf(w1, f1.y, w2 * f2.y));
        res.z = acc.z + b.z + fmaf(w0, f0.z, fmaf(w1, f1.z, w2 * f2.z));
        res.w = acc.w + b.w + fmaf(w0, f0.w, fmaf(w1, f1.w, w2 * f2.w));
        ((float4*)out)[q * 32 + c4] = res;
    }
}

extern "C" void kernel_launch(void* const* d_in, const int* in_sizes, int n_in,
                              void* d_out, int out_size, void* d_ws, size_t ws_size,
                              hipStream_t stream) {
    const float* up_points     = (const float*)d_in[0];
    const float* up_features   = (const float*)d_in[1];
    const float* down_points   = (const float*)d_in[2];
    const float* down_features = (const float*)d_in[3];
    const float* W_up          = (const float*)d_in[4];
    const float* b_up          = (const float*)d_in[5];
    const float* W_down        = (const float*)d_in[6];
    const float* b_down        = (const float*)d_in[7];
    float* out = (float*)d_out;

    float* wt_down = (float*)d_ws;                         // 256*128
    float* wt_up   = wt_down + DOWNC * OUTC;               // 128*128
    float* down_f  = wt_up + UPC * OUTC;                   // 8192*128
    float2* part   = (float2*)(down_f + N_DOWN * OUTC);    // NCHUNK*32768*3 float2
    // total ~10.7 MB (same footprint as the proven R0 layout)

    transpose_w<<<(DOWNC * OUTC + UPC * OUTC) / 256, 256, 0, stream>>>(
        W_up, W_down, wt_up, wt_down);
    down_proj<<<N_DOWN / 16, 256, 0, stream>>>(
        down_features, wt_down, b_down, down_f);
    knn_partial<<<dim3(M_UP / (256 * Q), NCHUNK), 256, 0, stream>>>(
        up_points, down_points, part);
    up_fused<<<M_UP / 16, 256, 0, stream>>>(
        up_features, wt_up, b_up, down_f, part, out);
}